// Round 6
// baseline (751.179 us; speedup 1.0000x reference)
//
#include <hip/hip_runtime.h>
#include <stdint.h>
#include <stddef.h>

#define NN 64
#define BB 128
#define LL 4096
#define EE 16

typedef __attribute__((ext_vector_type(4))) float f32x4;
typedef __attribute__((ext_vector_type(2))) float f32x2;
typedef __attribute__((ext_vector_type(8))) short short8;
typedef __attribute__((ext_vector_type(4))) unsigned short u16x4;

__device__ __forceinline__ unsigned short f2bf(float f) {
  union { float f; unsigned u; } v; v.f = f;
  unsigned r = v.u + 0x7FFFu + ((v.u >> 16) & 1u);   // RNE
  return (unsigned short)(r >> 16);
}
__device__ __forceinline__ float bf2f(unsigned short h) {
  union { unsigned u; float f; } v; v.u = ((unsigned)h) << 16;
  return v.f;
}
__device__ __forceinline__ void gload16(const void* g, void* l) {
  __builtin_amdgcn_global_load_lds((const __attribute__((address_space(1))) void*)g,
                                   (__attribute__((address_space(3))) void*)l,
                                   16, 0, 0);
}

#define MFMA(a, b, c) __builtin_amdgcn_mfma_f32_16x16x32_bf16((a), (b), (c), 0, 0, 0)

// ---------------- K1: Wm -> bf16 + Wl/Wr -> transposed bf16 ----------------
__global__ __launch_bounds__(256) void k_cvtw(const float* __restrict__ Wm,
    const float* __restrict__ Wl, const float* __restrict__ Wr,
    unsigned short* __restrict__ wm_bf, unsigned short* __restrict__ wt_bf) {
  int bid = blockIdx.x;
  if (bid < 2048) {
    int i = bid * 256 + threadIdx.x;
    for (; i < (LL * LL / 4); i += 2048 * 256) {
      f32x4 v = ((const f32x4*)Wm)[i];
      u16x4 o;
      o[0] = f2bf(v[0]); o[1] = f2bf(v[1]); o[2] = f2bf(v[2]); o[3] = f2bf(v[3]);
      ((u16x4*)wm_bf)[i] = o;
    }
  } else {
    // wt_bf[e][k]: e<16 -> Wl[k][e], e>=16 -> Wr[k][e-16]. 32x4096 bf16.
    int u = (bid - 2048) * 256 + threadIdx.x;   // 0..2047
    int e = u >> 6;
    int kb = (u & 63) * 64;
    const float* src = (e < 16) ? (Wl + e) : (Wr + (e - 16));
    for (int k = kb; k < kb + 64; ++k)
      wt_bf[(size_t)e * LL + k] = f2bf(src[(size_t)k * 16]);
  }
}

// ---------------- K2: fused feat->bf16 convert + MFMA att projections ----------------
__global__ __launch_bounds__(256) void k_attF(const float* __restrict__ feat,
    const unsigned short* __restrict__ wt_bf,
    unsigned short* __restrict__ feat_bf, float* __restrict__ attP) {
  __shared__ __align__(16) unsigned short alds[64 * 512];
  const int t = threadIdx.x, lane = t & 63, w = t >> 6;
  const int rowBase = blockIdx.x * 64;
  const int kBase = blockIdx.y * 2048;
  const int rr = lane & 15, gg8 = (lane >> 4) * 8;
  f32x4 acc0 = {}, acc1 = {};
  const unsigned short* b0P = wt_bf + (size_t)rr * LL;
  const unsigned short* b1P = wt_bf + (size_t)(16 + rr) * LL;
  for (int c = 0; c < 4; ++c) {
    const int k0 = kBase + c * 512;
    __syncthreads();
    #pragma unroll
    for (int u = 0; u < 32; ++u) {
      int unit = t + u * 256;
      int row = unit >> 7, col4 = unit & 127;
      size_t gi = (size_t)(rowBase + row) * LL + k0 + col4 * 4;
      f32x4 v = *(const f32x4*)&feat[gi];
      u16x4 o; o[0] = f2bf(v[0]); o[1] = f2bf(v[1]); o[2] = f2bf(v[2]); o[3] = f2bf(v[3]);
      *(u16x4*)&feat_bf[gi] = o;
      int byte = (row * 1024 + col4 * 8) ^ ((row & 7) << 4);
      *(u16x4*)((char*)alds + byte) = o;
    }
    __syncthreads();
    const int arow = w * 16 + rr;
    const char* aBase = (const char*)alds + arow * 1024;
    const int axor = (arow & 7) << 4;
    #pragma unroll 4
    for (int ks = 0; ks < 16; ++ks) {
      int abyte = ((ks * 32 + gg8) * 2) ^ axor;
      short8 av = *(const short8*)(aBase + abyte);
      short8 b0 = *(const short8*)(b0P + k0 + ks * 32 + gg8);
      short8 b1 = *(const short8*)(b1P + k0 + ks * 32 + gg8);
      acc0 = MFMA(av, b0, acc0);
      acc1 = MFMA(av, b1, acc1);
    }
  }
  const int orow = rowBase + w * 16 + (lane >> 4) * 4;
  float* P = attP + (size_t)blockIdx.y * (8192 * 32);
  #pragma unroll
  for (int j = 0; j < 4; ++j) {
    P[(size_t)(orow + j) * 32 + rr]      = acc0[j];
    P[(size_t)(orow + j) * 32 + 16 + rr] = acc1[j];
  }
}

// ---------------- K3: edge scores + BN + softmax (sums 2 attP partials) ----------------
__global__ __launch_bounds__(256) void k_edge(const float* __restrict__ attP,
    const float* __restrict__ bl, const float* __restrict__ br,
    const float* __restrict__ gamma, const float* __restrict__ beta,
    float* __restrict__ w_t) {
  __shared__ __align__(16) float attr[BB][20];
  __shared__ float el[NN][BB + 1];
  __shared__ float part[NN][4][2];
  __shared__ float sc[NN], sh[NN];
  int d = blockIdx.x, t = threadIdx.x;
  for (int i = t; i < 2048; i += 256) {
    int b = i >> 4, e = i & 15;
    float v2 = br[e];
    #pragma unroll
    for (int c = 0; c < 2; ++c)
      v2 += attP[(size_t)c * (8192 * 32) + ((size_t)d * 128 + b) * 32 + 16 + e];
    attr[b][e] = v2;
  }
  float blv[16];
  #pragma unroll
  for (int e = 0; e < 16; ++e) blv[e] = bl[e];
  __syncthreads();
  for (int v = t; v < NN * BB; v += 256) {
    int s = v >> 7, b = v & 127;
    float al[16];
    #pragma unroll
    for (int e = 0; e < 16; ++e) al[e] = blv[e];
    #pragma unroll
    for (int c = 0; c < 2; ++c) {
      const f32x4* p = (const f32x4*)&attP[(size_t)c * (8192 * 32) + ((size_t)s * 128 + b) * 32];
      #pragma unroll
      for (int q = 0; q < 4; ++q) {
        f32x4 x = p[q];
        al[q * 4 + 0] += x[0]; al[q * 4 + 1] += x[1];
        al[q * 4 + 2] += x[2]; al[q * 4 + 3] += x[3];
      }
    }
    float acc = 0.f;
    #pragma unroll
    for (int e = 0; e < 16; ++e) acc += al[e] * attr[b][e];
    el[s][b] = acc;
  }
  __syncthreads();
  {
    int s = t >> 2, q = t & 3;
    float sum = 0.f, ss = 0.f;
    for (int b = q * 32; b < q * 32 + 32; ++b) { float x = el[s][b]; sum += x; ss += x * x; }
    part[s][q][0] = sum; part[s][q][1] = ss;
  }
  __syncthreads();
  if (t < 64) {
    float sum = 0.f, ss = 0.f;
    #pragma unroll
    for (int q = 0; q < 4; ++q) { sum += part[t][q][0]; ss += part[t][q][1]; }
    float mu = sum * (1.f / 128.f);
    float var = ss * (1.f / 128.f) - mu * mu;
    int c = d * 64 + t;
    float a = gamma[c] * rsqrtf(fmaxf(var, 0.f) + 1e-5f);
    sc[t] = a; sh[t] = beta[c] - mu * a;
  }
  __syncthreads();
  if (t < 128) {
    int b = t;
    float y[64];
    float m = -1e30f;
    #pragma unroll
    for (int s = 0; s < 64; ++s) { y[s] = sc[s] * el[s][b] + sh[s]; m = fmaxf(m, y[s]); }
    float sum = 0.f;
    #pragma unroll
    for (int s = 0; s < 64; ++s) { y[s] = __expf(y[s] - m); sum += y[s]; }
    float inv = 1.f / sum;
    float* wp = &w_t[((size_t)b * 64 + d) * 64];
    #pragma unroll
    for (int s4 = 0; s4 < 16; ++s4) {
      f32x4 o;
      o[0] = y[s4 * 4 + 0] * inv; o[1] = y[s4 * 4 + 1] * inv;
      o[2] = y[s4 * 4 + 2] * inv; o[3] = y[s4 * 4 + 3] * inv;
      *(f32x4*)&wp[s4 * 4] = o;
    }
  }
}

// ---------------- K4: 256x256 bf16 MFMA GEMM, register read-ahead pipeline ----------------
// R5->R6: reads for phase p+1 issue DURING phase p's MFMA (named reg sets
// aA/aB/bA/bB, verified lifetimes), ONE barrier per phase (4/K-tile, was 8).
// Stage ring: P0->A-k1[t+1], P1->B-k1[t+1], P2->A-k0[t+2], P3->B-k0[t+2]
// (1 pair/phase); VM6 at end-P0/end-P2 (tail VM4/VM0 derived slot-by-slot).
#define LDS_A 0
#define LDS_B 65536
#define BAR   __builtin_amdgcn_s_barrier()
#define VM8   asm volatile("s_waitcnt vmcnt(8)" ::: "memory")
#define VM6   asm volatile("s_waitcnt vmcnt(6)" ::: "memory")
#define VM4   asm volatile("s_waitcnt vmcnt(4)" ::: "memory")
#define VM0   asm volatile("s_waitcnt vmcnt(0)" ::: "memory")
#define PRIO1 __builtin_amdgcn_s_setprio(1)
#define PRIO0 __builtin_amdgcn_s_setprio(0)
#define STAGE2(g0, g1, ldsoff) do { \
    gload16((g0), lds_raw + (ldsoff) + tid16); \
    gload16((g1), lds_raw + (ldsoff) + 8192 + tid16); } while (0)

__global__ __launch_bounds__(512, 2) void k_gemm8(const unsigned short* __restrict__ A,
    const unsigned short* __restrict__ Bm, const float* __restrict__ bm,
    unsigned short* __restrict__ C) {
  __shared__ __align__(16) char lds_raw[131072];
  const int tid = threadIdx.x;
  const int lane = tid & 63, wave = tid >> 6;
  const int wm = wave >> 2, wn = wave & 3;
  int bid = blockIdx.x;
  int swz = (bid & 7) * 64 + (bid >> 3);
  int tM = swz >> 4, tN = swz & 15;
  const size_t rowBase = (size_t)tM * 256, colBase = (size_t)tN * 256;
  const int tid16 = tid * 16;
  const int o0 = tid16, o1 = tid16 + 8192;
  const int r0s = (o0 & 1023) >> 6, r1s = (o1 & 1023) >> 6;
  const int row0 = (o0 >> 10) * 16 + r0s, row1 = (o1 >> 10) * 16 + r1s;
  const int col0 = (((o0 >> 4) & 3) ^ ((r0s >> 3) << 1)) * 8;
  const int col1 = (((o1 >> 4) & 3) ^ ((r1s >> 3) << 1)) * 8;
  const unsigned short* aR0 = A  + (rowBase + row0) * LL + col0;
  const unsigned short* aR1 = A  + (rowBase + row1) * LL + col1;
  const unsigned short* bR0 = Bm + (colBase + row0) * LL + col0;
  const unsigned short* bR1 = Bm + (colBase + row1) * LL + col1;
  const int rr = lane & 15, gg = lane >> 4;
  const int rdswz = rr * 64 + ((gg ^ ((rr >> 3) << 1)) << 4);
  f32x4 acc[8][4] = {};
  short8 aA[4], aB[4], bA[4], bB[4];
  // ---- prologue: 6 pairs; first 2 landed via VM8 ----
  STAGE2(aR0 +  0, aR1 +  0, LDS_A + 0);             // A-k0[0]
  STAGE2(bR0 +  0, bR1 +  0, LDS_B + 0);             // B-k0[0]
  STAGE2(aR0 + 32, aR1 + 32, LDS_A + 16384);         // A-k1[0]
  STAGE2(bR0 + 32, bR1 + 32, LDS_B + 16384);         // B-k1[0]
  STAGE2(aR0 + 64, aR1 + 64, LDS_A + 32768);         // A-k0[1]
  STAGE2(bR0 + 64, bR1 + 64, LDS_B + 32768);         // B-k0[1]
  VM8;
  BAR;
  {
    const char* pA0 = lds_raw + LDS_A + wm * 8192 + rdswz;
    const char* pB0 = lds_raw + LDS_B + wn * 4096 + rdswz;
    #pragma unroll
    for (int i = 0; i < 4; ++i) aA[i] = *(const short8*)(pA0 + i * 1024);
    #pragma unroll
    for (int j = 0; j < 4; ++j) bA[j] = *(const short8*)(pB0 + j * 1024);
  }
  #pragma unroll 2
  for (int t = 0; t < 64; ++t) {
    const int d = t & 1;
    const char* pA  = lds_raw + LDS_A + d * 32768 + wm * 8192 + rdswz;
    const char* pB  = lds_raw + LDS_B + d * 32768 + wn * 4096 + rdswz;
    const char* pA2 = lds_raw + LDS_A + (d ^ 1) * 32768 + wm * 8192 + rdswz;
    const char* pB2 = lds_raw + LDS_B + (d ^ 1) * 32768 + wn * 4096 + rdswz;
    // ---- P0: read aB=A-k0 mi4-7; stage A-k1[t+1]; MFMA aA x bA -> acc[0-3] ----
    #pragma unroll
    for (int i = 0; i < 4; ++i) aB[i] = *(const short8*)(pA + 4096 + i * 1024);
    if (t <= 62) { size_t kk = (size_t)(t + 1) * 64 + 32;
      STAGE2(aR0 + kk, aR1 + kk, LDS_A + ((t + 1) & 1) * 32768 + 16384); }
    PRIO1;
    #pragma unroll
    for (int i = 0; i < 4; ++i) {
      acc[i][0] = MFMA(aA[i], bA[0], acc[i][0]);
      acc[i][1] = MFMA(aA[i], bA[1], acc[i][1]);
      acc[i][2] = MFMA(aA[i], bA[2], acc[i][2]);
      acc[i][3] = MFMA(aA[i], bA[3], acc[i][3]);
    }
    PRIO0;
    if (t <= 62) { VM6; } else { VM0; }
    BAR;
    // ---- P1: read aA=A-k1 mi0-3, bB=B-k1; stage B-k1[t+1]; MFMA aB x bA -> acc[4-7] ----
    #pragma unroll
    for (int i = 0; i < 4; ++i) aA[i] = *(const short8*)(pA + 16384 + i * 1024);
    #pragma unroll
    for (int j = 0; j < 4; ++j) bB[j] = *(const short8*)(pB + 16384 + j * 1024);
    if (t <= 62) { size_t kk = (size_t)(t + 1) * 64 + 32;
      STAGE2(bR0 + kk, bR1 + kk, LDS_B + ((t + 1) & 1) * 32768 + 16384); }
    PRIO1;
    #pragma unroll
    for (int i = 0; i < 4; ++i) {
      acc[4 + i][0] = MFMA(aB[i], bA[0], acc[4 + i][0]);
      acc[4 + i][1] = MFMA(aB[i], bA[1], acc[4 + i][1]);
      acc[4 + i][2] = MFMA(aB[i], bA[2], acc[4 + i][2]);
      acc[4 + i][3] = MFMA(aB[i], bA[3], acc[4 + i][3]);
    }
    PRIO0; BAR;
    // ---- P2: read aB=A-k1 mi4-7; stage A-k0[t+2]; MFMA aA x bB -> acc[0-3] ----
    #pragma unroll
    for (int i = 0; i < 4; ++i) aB[i] = *(const short8*)(pA + 16384 + 4096 + i * 1024);
    if (t <= 61) { size_t kk = (size_t)(t + 2) * 64;
      STAGE2(aR0 + kk, aR1 + kk, LDS_A + d * 32768); }
    PRIO1;
    #pragma unroll
    for (int i = 0; i < 4; ++i) {
      acc[i][0] = MFMA(aA[i], bB[0], acc[i][0]);
      acc[i][1] = MFMA(aA[i], bB[1], acc[i][1]);
      acc[i][2] = MFMA(aA[i], bB[2], acc[i][2]);
      acc[i][3] = MFMA(aA[i], bB[3], acc[i][3]);
    }
    PRIO0;
    if (t <= 61) { VM6; } else if (t == 62) { VM4; } else { VM0; }
    BAR;
    // ---- P3: read aA=A-k0[t+1] mi0-3, bA=B-k0[t+1]; stage B-k0[t+2]; MFMA aB x bB -> acc[4-7] ----
    if (t < 63) {
      #pragma unroll
      for (int i = 0; i < 4; ++i) aA[i] = *(const short8*)(pA2 + i * 1024);
      #pragma unroll
      for (int j = 0; j < 4; ++j) bA[j] = *(const short8*)(pB2 + j * 1024);
    }
    if (t <= 61) { size_t kk = (size_t)(t + 2) * 64;
      STAGE2(bR0 + kk, bR1 + kk, LDS_B + d * 32768); }
    PRIO1;
    #pragma unroll
    for (int i = 0; i < 4; ++i) {
      acc[4 + i][0] = MFMA(aB[i], bB[0], acc[4 + i][0]);
      acc[4 + i][1] = MFMA(aB[i], bB[1], acc[4 + i][1]);
      acc[4 + i][2] = MFMA(aB[i], bB[2], acc[4 + i][2]);
      acc[4 + i][3] = MFMA(aB[i], bB[3], acc[4 + i][3]);
    }
    PRIO0; BAR;
  }
  VM0;
  // ---- epilogue: +bm, ReLU, bf16 store ----
  const int co = lane & 15, ro4 = (lane >> 4) * 4;
  #pragma unroll
  for (int mig = 0; mig < 8; ++mig) {
    size_t r0 = rowBase + (size_t)wm * 128 + mig * 16 + ro4;
    #pragma unroll
    for (int nj = 0; nj < 4; ++nj) {
      size_t c = colBase + (size_t)wn * 64 + nj * 16 + co;
      float bc = bm[c];
      #pragma unroll
      for (int j = 0; j < 4; ++j) {
        float v = acc[mig][nj][j] + bc;
        v = fmaxf(v, 0.f);
        C[(r0 + j) * LL + c] = f2bf(v);
      }
    }
  }
}

// ---------------- K5: aggregation ----------------
__global__ __launch_bounds__(256) void k_agg2(const float* __restrict__ w_t,
    const unsigned short* __restrict__ outb, const float* __restrict__ bias,
    float* __restrict__ rst) {
  int b = blockIdx.y;
  int t = threadIdx.x;
  int l0 = blockIdx.x * 512 + t * 2;
  float oA[64], oB[64];
  #pragma unroll
  for (int s = 0; s < 64; ++s) {
    unsigned u = *(const unsigned*)&outb[((size_t)s * BB + b) * LL + l0];
    oA[s] = bf2f((unsigned short)(u & 0xFFFF));
    oB[s] = bf2f((unsigned short)(u >> 16));
  }
  const float* wb = w_t + (size_t)b * 4096;
  float bs0 = bias[l0], bs1 = bias[l0 + 1];
  #pragma unroll 2
  for (int d = 0; d < 64; ++d) {
    const float* wr = wb + d * 64;
    float a0 = 0.f, a1 = 0.f;
    #pragma unroll
    for (int q = 0; q < 16; ++q) {
      f32x4 wq = *(const f32x4*)&wr[q * 4];
      #pragma unroll
      for (int j = 0; j < 4; ++j) {
        float wv = wq[j];
        a0 += wv * oA[q * 4 + j];
        a1 += wv * oB[q * 4 + j];
      }
    }
    f32x2 o; o[0] = a0 + bs0; o[1] = a1 + bs1;
    *(f32x2*)&rst[((size_t)d * BB + b) * LL + l0] = o;
  }
}

extern "C" void kernel_launch(void* const* d_in, const int* in_sizes, int n_in,
                              void* d_out, int out_size, void* d_ws, size_t ws_size,
                              hipStream_t stream) {
  (void)in_sizes; (void)n_in; (void)out_size; (void)ws_size;
  const float* feat  = (const float*)d_in[0];
  const float* Wl    = (const float*)d_in[1];
  const float* bl    = (const float*)d_in[2];
  const float* Wr    = (const float*)d_in[3];
  const float* br    = (const float*)d_in[4];
  const float* Wm    = (const float*)d_in[5];
  const float* bm    = (const float*)d_in[6];
  const float* gamma = (const float*)d_in[7];
  const float* beta  = (const float*)d_in[8];
  const float* bias  = (const float*)d_in[9];
  char* ws = (char*)d_ws;
  unsigned short* feat_bf = (unsigned short*)(ws);                 // 67,108,864
  unsigned short* wm_bf   = (unsigned short*)(ws + 67108864ull);   // 33,554,432
  unsigned short* out_bf  = (unsigned short*)(ws + 100663296ull);  // 67,108,864
  float* attP  = (float*)(ws + 167772160ull);                      //  2,097,152
  float* w_t   = (float*)(ws + 169869312ull);                      //  2,097,152
  unsigned short* wt_bf = (unsigned short*)(ws + 171966464ull);    //    262,144
  float* rst = (float*)d_out;

  k_cvtw<<<dim3(2056), dim3(256), 0, stream>>>(Wm, Wl, Wr, wm_bf, wt_bf);
  k_attF<<<dim3(128, 2), dim3(256), 0, stream>>>(feat, wt_bf, feat_bf, attP);
  k_edge<<<dim3(64), dim3(256), 0, stream>>>(attP, bl, br, gamma, beta, w_t);
  k_gemm8<<<dim3(512), dim3(512), 0, stream>>>(feat_bf, wm_bf, bm, out_bf);
  k_agg2<<<dim3(8, 128), dim3(256), 0, stream>>>(w_t, out_bf, bias, rst);
}

// Round 7
// 466.223 us; speedup vs baseline: 1.6112x; 1.6112x over previous
//
#include <hip/hip_runtime.h>
#include <stdint.h>
#include <stddef.h>

#define NN 64
#define BB 128
#define LL 4096
#define EE 16

typedef __attribute__((ext_vector_type(4))) float f32x4;
typedef __attribute__((ext_vector_type(2))) float f32x2;
typedef __attribute__((ext_vector_type(8))) short short8;
typedef __attribute__((ext_vector_type(4))) unsigned short u16x4;

__device__ __forceinline__ unsigned short f2bf(float f) {
  union { float f; unsigned u; } v; v.f = f;
  unsigned r = v.u + 0x7FFFu + ((v.u >> 16) & 1u);   // RNE
  return (unsigned short)(r >> 16);
}
__device__ __forceinline__ float bf2f(unsigned short h) {
  union { unsigned u; float f; } v; v.u = ((unsigned)h) << 16;
  return v.f;
}
__device__ __forceinline__ void gload16(const void* g, void* l) {
  __builtin_amdgcn_global_load_lds((const __attribute__((address_space(1))) void*)g,
                                   (__attribute__((address_space(3))) void*)l,
                                   16, 0, 0);
}

#define MFMA(a, b, c) __builtin_amdgcn_mfma_f32_16x16x32_bf16((a), (b), (c), 0, 0, 0)

// ---------------- K1: Wm -> bf16 + Wl/Wr -> transposed bf16 ----------------
__global__ __launch_bounds__(256) void k_cvtw(const float* __restrict__ Wm,
    const float* __restrict__ Wl, const float* __restrict__ Wr,
    unsigned short* __restrict__ wm_bf, unsigned short* __restrict__ wt_bf) {
  int bid = blockIdx.x;
  if (bid < 2048) {
    int i = bid * 256 + threadIdx.x;
    for (; i < (LL * LL / 4); i += 2048 * 256) {
      f32x4 v = ((const f32x4*)Wm)[i];
      u16x4 o;
      o[0] = f2bf(v[0]); o[1] = f2bf(v[1]); o[2] = f2bf(v[2]); o[3] = f2bf(v[3]);
      ((u16x4*)wm_bf)[i] = o;
    }
  } else {
    // wt_bf[e][k]: e<16 -> Wl[k][e], e>=16 -> Wr[k][e-16]. 32x4096 bf16.
    int u = (bid - 2048) * 256 + threadIdx.x;   // 0..2047
    int e = u >> 6;
    int kb = (u & 63) * 64;
    const float* src = (e < 16) ? (Wl + e) : (Wr + (e - 16));
    for (int k = kb; k < kb + 64; ++k)
      wt_bf[(size_t)e * LL + k] = f2bf(src[(size_t)k * 16]);
  }
}

// ---------------- K2: fused feat->bf16 convert + MFMA att projections ----------------
__global__ __launch_bounds__(256) void k_attF(const float* __restrict__ feat,
    const unsigned short* __restrict__ wt_bf,
    unsigned short* __restrict__ feat_bf, float* __restrict__ attP) {
  __shared__ __align__(16) unsigned short alds[64 * 512];
  const int t = threadIdx.x, lane = t & 63, w = t >> 6;
  const int rowBase = blockIdx.x * 64;
  const int kBase = blockIdx.y * 2048;
  const int rr = lane & 15, gg8 = (lane >> 4) * 8;
  f32x4 acc0 = {}, acc1 = {};
  const unsigned short* b0P = wt_bf + (size_t)rr * LL;
  const unsigned short* b1P = wt_bf + (size_t)(16 + rr) * LL;
  for (int c = 0; c < 4; ++c) {
    const int k0 = kBase + c * 512;
    __syncthreads();
    #pragma unroll
    for (int u = 0; u < 32; ++u) {
      int unit = t + u * 256;
      int row = unit >> 7, col4 = unit & 127;
      size_t gi = (size_t)(rowBase + row) * LL + k0 + col4 * 4;
      f32x4 v = *(const f32x4*)&feat[gi];
      u16x4 o; o[0] = f2bf(v[0]); o[1] = f2bf(v[1]); o[2] = f2bf(v[2]); o[3] = f2bf(v[3]);
      *(u16x4*)&feat_bf[gi] = o;
      int byte = (row * 1024 + col4 * 8) ^ ((row & 7) << 4);
      *(u16x4*)((char*)alds + byte) = o;
    }
    __syncthreads();
    const int arow = w * 16 + rr;
    const char* aBase = (const char*)alds + arow * 1024;
    const int axor = (arow & 7) << 4;
    #pragma unroll 4
    for (int ks = 0; ks < 16; ++ks) {
      int abyte = ((ks * 32 + gg8) * 2) ^ axor;
      short8 av = *(const short8*)(aBase + abyte);
      short8 b0 = *(const short8*)(b0P + k0 + ks * 32 + gg8);
      short8 b1 = *(const short8*)(b1P + k0 + ks * 32 + gg8);
      acc0 = MFMA(av, b0, acc0);
      acc1 = MFMA(av, b1, acc1);
    }
  }
  const int orow = rowBase + w * 16 + (lane >> 4) * 4;
  float* P = attP + (size_t)blockIdx.y * (8192 * 32);
  #pragma unroll
  for (int j = 0; j < 4; ++j) {
    P[(size_t)(orow + j) * 32 + rr]      = acc0[j];
    P[(size_t)(orow + j) * 32 + 16 + rr] = acc1[j];
  }
}

// ---------------- K3: edge scores + BN + softmax (sums 2 attP partials) ----------------
__global__ __launch_bounds__(256) void k_edge(const float* __restrict__ attP,
    const float* __restrict__ bl, const float* __restrict__ br,
    const float* __restrict__ gamma, const float* __restrict__ beta,
    float* __restrict__ w_t) {
  __shared__ __align__(16) float attr[BB][20];
  __shared__ float el[NN][BB + 1];
  __shared__ float part[NN][4][2];
  __shared__ float sc[NN], sh[NN];
  int d = blockIdx.x, t = threadIdx.x;
  for (int i = t; i < 2048; i += 256) {
    int b = i >> 4, e = i & 15;
    float v2 = br[e];
    #pragma unroll
    for (int c = 0; c < 2; ++c)
      v2 += attP[(size_t)c * (8192 * 32) + ((size_t)d * 128 + b) * 32 + 16 + e];
    attr[b][e] = v2;
  }
  float blv[16];
  #pragma unroll
  for (int e = 0; e < 16; ++e) blv[e] = bl[e];
  __syncthreads();
  for (int v = t; v < NN * BB; v += 256) {
    int s = v >> 7, b = v & 127;
    float al[16];
    #pragma unroll
    for (int e = 0; e < 16; ++e) al[e] = blv[e];
    #pragma unroll
    for (int c = 0; c < 2; ++c) {
      const f32x4* p = (const f32x4*)&attP[(size_t)c * (8192 * 32) + ((size_t)s * 128 + b) * 32];
      #pragma unroll
      for (int q = 0; q < 4; ++q) {
        f32x4 x = p[q];
        al[q * 4 + 0] += x[0]; al[q * 4 + 1] += x[1];
        al[q * 4 + 2] += x[2]; al[q * 4 + 3] += x[3];
      }
    }
    float acc = 0.f;
    #pragma unroll
    for (int e = 0; e < 16; ++e) acc += al[e] * attr[b][e];
    el[s][b] = acc;
  }
  __syncthreads();
  {
    int s = t >> 2, q = t & 3;
    float sum = 0.f, ss = 0.f;
    for (int b = q * 32; b < q * 32 + 32; ++b) { float x = el[s][b]; sum += x; ss += x * x; }
    part[s][q][0] = sum; part[s][q][1] = ss;
  }
  __syncthreads();
  if (t < 64) {
    float sum = 0.f, ss = 0.f;
    #pragma unroll
    for (int q = 0; q < 4; ++q) { sum += part[t][q][0]; ss += part[t][q][1]; }
    float mu = sum * (1.f / 128.f);
    float var = ss * (1.f / 128.f) - mu * mu;
    int c = d * 64 + t;
    float a = gamma[c] * rsqrtf(fmaxf(var, 0.f) + 1e-5f);
    sc[t] = a; sh[t] = beta[c] - mu * a;
  }
  __syncthreads();
  if (t < 128) {
    int b = t;
    float y[64];
    float m = -1e30f;
    #pragma unroll
    for (int s = 0; s < 64; ++s) { y[s] = sc[s] * el[s][b] + sh[s]; m = fmaxf(m, y[s]); }
    float sum = 0.f;
    #pragma unroll
    for (int s = 0; s < 64; ++s) { y[s] = __expf(y[s] - m); sum += y[s]; }
    float inv = 1.f / sum;
    float* wp = &w_t[((size_t)b * 64 + d) * 64];
    #pragma unroll
    for (int s4 = 0; s4 < 16; ++s4) {
      f32x4 o;
      o[0] = y[s4 * 4 + 0] * inv; o[1] = y[s4 * 4 + 1] * inv;
      o[2] = y[s4 * 4 + 2] * inv; o[3] = y[s4 * 4 + 3] * inv;
      *(f32x4*)&wp[s4 * 4] = o;
    }
  }
}

// ---------------- K4: 128x256 bf16 MFMA GEMM, 2 blocks/CU, 3-buffer ring ----------------
// R6->R7: cross-BLOCK overlap instead of register pipelining (R6 spilled).
// 4 waves (2Mx2N, 64x128/wave, acc=128), BK=32, LDS 72KB (3-slot ring for
// A[128x32] + B[256x32]) -> 2 blocks/CU. Per K-tile: 12 ds_read -> stage
// t+2 into ring slot (6 gloads) -> 32 MFMA -> vmcnt(6) -> ONE barrier.
// Read-drain before barrier is implied by MFMA consumption (compiler
// waitcnt); slot written at t was last read at t-1 -> safe.
#define BAR   __builtin_amdgcn_s_barrier()
#define VM6   asm volatile("s_waitcnt vmcnt(6)" ::: "memory")
#define VM0   asm volatile("s_waitcnt vmcnt(0)" ::: "memory")
#define NOVM  do {} while (0)
#define PRIO1 __builtin_amdgcn_s_setprio(1)
#define PRIO0 __builtin_amdgcn_s_setprio(0)

#define STAGE6(STG, KK) do { \
    gload16(aG0 + (KK),            ldsm + (STG) * 8192 + tid16); \
    gload16(aG0 + 64 * LL + (KK),  ldsm + (STG) * 8192 + 4096 + tid16); \
    gload16(bG0 + (KK),            ldsm + 24576 + (STG) * 16384 + tid16); \
    gload16(bG0 + 64 * LL + (KK),  ldsm + 24576 + (STG) * 16384 + 4096 + tid16); \
    gload16(bG0 + 128 * LL + (KK), ldsm + 24576 + (STG) * 16384 + 8192 + tid16); \
    gload16(bG0 + 192 * LL + (KK), ldsm + 24576 + (STG) * 16384 + 12288 + tid16); \
  } while (0)

#define GITER(T, CUR, STG, DOSTAGE, VMW) do { \
    const char* pA = ldsm + (CUR) * 8192 + wm * 4096 + rdswz; \
    const char* pB = ldsm + 24576 + (CUR) * 16384 + wn * 8192 + rdswz; \
    short8 af[4], bf[8]; \
    _Pragma("unroll") for (int mi = 0; mi < 4; ++mi) af[mi] = *(const short8*)(pA + mi * 1024); \
    _Pragma("unroll") for (int nj = 0; nj < 8; ++nj) bf[nj] = *(const short8*)(pB + nj * 1024); \
    if (DOSTAGE) { STAGE6(STG, (size_t)((T) + 2) * 32); } \
    PRIO1; \
    _Pragma("unroll") for (int mi = 0; mi < 4; ++mi) \
      _Pragma("unroll") for (int nj = 0; nj < 8; ++nj) \
        acc[mi][nj] = MFMA(af[mi], bf[nj], acc[mi][nj]); \
    PRIO0; VMW; BAR; \
  } while (0)

__global__ __launch_bounds__(256, 2) void k_gemmW(const unsigned short* __restrict__ A,
    const unsigned short* __restrict__ Bm, const float* __restrict__ bm,
    unsigned short* __restrict__ C) {
  __shared__ __align__(16) char ldsm[73728];
  const int tid = threadIdx.x;
  const int lane = tid & 63, wave = tid >> 6;
  const int wm = wave >> 1, wn = wave & 1;
  int bid = blockIdx.x;
  int swz = (bid & 7) * 128 + (bid >> 3);   // 1024 % 8 == 0, bijective
  int tM = swz >> 4, tN = swz & 15;
  const size_t rowBase = (size_t)tM * 128, colBase = (size_t)tN * 256;
  // staging decode (inverse XOR swizzle; LDS dest linear)
  const int tid16 = tid * 16;
  const int srow = tid >> 2;                               // 0..63
  const int qx = (tid & 3) ^ (((tid >> 5) & 1) << 1);      // swizzled 16B slot
  const unsigned short* aG0 = A  + (rowBase + srow) * LL + qx * 8;
  const unsigned short* bG0 = Bm + (colBase + srow) * LL + qx * 8;
  // ds_read swizzled lane base (rows 64B, XOR bit3-of-row into 16B-slot bit1)
  const int rr = lane & 15, gg = lane >> 4;
  const int rdswz = rr * 64 + ((gg ^ ((rr >> 3) << 1)) << 4);
  f32x4 acc[4][8] = {};
  // ---- prologue: stage t0 -> slot0, t1 -> slot1 ----
  STAGE6(0, 0);
  STAGE6(1, 32);
  VM6;
  BAR;
  // ---- main loop: 128 K-tiles, ring slots (t%3), stage t+2 ----
  for (int tb = 0; tb < 126; tb += 3) {
    GITER(tb,     0, 2, 1, VM6);
    GITER(tb + 1, 1, 0, 1, VM6);
    GITER(tb + 2, 2, 1, 1, VM6);
  }
  GITER(126, 0, 0, 0, VM0);
  GITER(127, 1, 0, 0, NOVM);
  // ---- epilogue: +bm, ReLU, bf16 store ----
  const int co = lane & 15, ro4 = (lane >> 4) * 4;
  #pragma unroll
  for (int mig = 0; mig < 4; ++mig) {
    size_t r0 = rowBase + (size_t)wm * 64 + mig * 16 + ro4;
    #pragma unroll
    for (int nj = 0; nj < 8; ++nj) {
      size_t c = colBase + (size_t)wn * 128 + nj * 16 + co;
      float bc = bm[c];
      #pragma unroll
      for (int j = 0; j < 4; ++j) {
        float v = acc[mig][nj][j] + bc;
        v = fmaxf(v, 0.f);
        C[(r0 + j) * LL + c] = f2bf(v);
      }
    }
  }
}

// ---------------- K5: aggregation ----------------
__global__ __launch_bounds__(256) void k_agg2(const float* __restrict__ w_t,
    const unsigned short* __restrict__ outb, const float* __restrict__ bias,
    float* __restrict__ rst) {
  int b = blockIdx.y;
  int t = threadIdx.x;
  int l0 = blockIdx.x * 512 + t * 2;
  float oA[64], oB[64];
  #pragma unroll
  for (int s = 0; s < 64; ++s) {
    unsigned u = *(const unsigned*)&outb[((size_t)s * BB + b) * LL + l0];
    oA[s] = bf2f((unsigned short)(u & 0xFFFF));
    oB[s] = bf2f((unsigned short)(u >> 16));
  }
  const float* wb = w_t + (size_t)b * 4096;
  float bs0 = bias[l0], bs1 = bias[l0 + 1];
  #pragma unroll 2
  for (int d = 0; d < 64; ++d) {
    const float* wr = wb + d * 64;
    float a0 = 0.f, a1 = 0.f;
    #pragma unroll
    for (int q = 0; q < 16; ++q) {
      f32x4 wq = *(const f32x4*)&wr[q * 4];
      #pragma unroll
      for (int j = 0; j < 4; ++j) {
        float wv = wq[j];
        a0 += wv * oA[q * 4 + j];
        a1 += wv * oB[q * 4 + j];
      }
    }
    f32x2 o; o[0] = a0 + bs0; o[1] = a1 + bs1;
    *(f32x2*)&rst[((size_t)d * BB + b) * LL + l0] = o;
  }
}

extern "C" void kernel_launch(void* const* d_in, const int* in_sizes, int n_in,
                              void* d_out, int out_size, void* d_ws, size_t ws_size,
                              hipStream_t stream) {
  (void)in_sizes; (void)n_in; (void)out_size; (void)ws_size;
  const float* feat  = (const float*)d_in[0];
  const float* Wl    = (const float*)d_in[1];
  const float* bl    = (const float*)d_in[2];
  const float* Wr    = (const float*)d_in[3];
  const float* br    = (const float*)d_in[4];
  const float* Wm    = (const float*)d_in[5];
  const float* bm    = (const float*)d_in[6];
  const float* gamma = (const float*)d_in[7];
  const float* beta  = (const float*)d_in[8];
  const float* bias  = (const float*)d_in[9];
  char* ws = (char*)d_ws;
  unsigned short* feat_bf = (unsigned short*)(ws);                 // 67,108,864
  unsigned short* wm_bf   = (unsigned short*)(ws + 67108864ull);   // 33,554,432
  unsigned short* out_bf  = (unsigned short*)(ws + 100663296ull);  // 67,108,864
  float* attP  = (float*)(ws + 167772160ull);                      //  2,097,152
  float* w_t   = (float*)(ws + 169869312ull);                      //  2,097,152
  unsigned short* wt_bf = (unsigned short*)(ws + 171966464ull);    //    262,144
  float* rst = (float*)d_out;

  k_cvtw<<<dim3(2056), dim3(256), 0, stream>>>(Wm, Wl, Wr, wm_bf, wt_bf);
  k_attF<<<dim3(128, 2), dim3(256), 0, stream>>>(feat, wt_bf, feat_bf, attP);
  k_edge<<<dim3(64), dim3(256), 0, stream>>>(attP, bl, br, gamma, beta, w_t);
  k_gemmW<<<dim3(1024), dim3(256), 0, stream>>>(feat_bf, wm_bf, bm, out_bf);
  k_agg2<<<dim3(8, 128), dim3(256), 0, stream>>>(w_t, out_bf, bias, rst);
}

// Round 8
// 463.078 us; speedup vs baseline: 1.6221x; 1.0068x over previous
//
#include <hip/hip_runtime.h>
#include <stdint.h>
#include <stddef.h>

#define NN 64
#define BB 128
#define LL 4096
#define EE 16

typedef __attribute__((ext_vector_type(4))) float f32x4;
typedef __attribute__((ext_vector_type(16))) float f32x16;
typedef __attribute__((ext_vector_type(2))) float f32x2;
typedef __attribute__((ext_vector_type(8))) short short8;
typedef __attribute__((ext_vector_type(4))) unsigned short u16x4;

__device__ __forceinline__ unsigned short f2bf(float f) {
  union { float f; unsigned u; } v; v.f = f;
  unsigned r = v.u + 0x7FFFu + ((v.u >> 16) & 1u);   // RNE
  return (unsigned short)(r >> 16);
}
__device__ __forceinline__ float bf2f(unsigned short h) {
  union { unsigned u; float f; } v; v.u = ((unsigned)h) << 16;
  return v.f;
}
__device__ __forceinline__ void gload16(const void* g, void* l) {
  __builtin_amdgcn_global_load_lds((const __attribute__((address_space(1))) void*)g,
                                   (__attribute__((address_space(3))) void*)l,
                                   16, 0, 0);
}

#define MFMA(a, b, c)   __builtin_amdgcn_mfma_f32_16x16x32_bf16((a), (b), (c), 0, 0, 0)
#define MFMA32(a, b, c) __builtin_amdgcn_mfma_f32_32x32x16_bf16((a), (b), (c), 0, 0, 0)

// ---------------- K1: Wm -> bf16 + Wl/Wr -> transposed bf16 ----------------
__global__ __launch_bounds__(256) void k_cvtw(const float* __restrict__ Wm,
    const float* __restrict__ Wl, const float* __restrict__ Wr,
    unsigned short* __restrict__ wm_bf, unsigned short* __restrict__ wt_bf) {
  int bid = blockIdx.x;
  if (bid < 2048) {
    int i = bid * 256 + threadIdx.x;
    for (; i < (LL * LL / 4); i += 2048 * 256) {
      f32x4 v = ((const f32x4*)Wm)[i];
      u16x4 o;
      o[0] = f2bf(v[0]); o[1] = f2bf(v[1]); o[2] = f2bf(v[2]); o[3] = f2bf(v[3]);
      ((u16x4*)wm_bf)[i] = o;
    }
  } else {
    int u = (bid - 2048) * 256 + threadIdx.x;   // 0..2047
    int e = u >> 6;
    int kb = (u & 63) * 64;
    const float* src = (e < 16) ? (Wl + e) : (Wr + (e - 16));
    for (int k = kb; k < kb + 64; ++k)
      wt_bf[(size_t)e * LL + k] = f2bf(src[(size_t)k * 16]);
  }
}

// ---------------- K2: fused feat->bf16 convert + MFMA att projections ----------------
__global__ __launch_bounds__(256) void k_attF(const float* __restrict__ feat,
    const unsigned short* __restrict__ wt_bf,
    unsigned short* __restrict__ feat_bf, float* __restrict__ attP) {
  __shared__ __align__(16) unsigned short alds[64 * 512];
  const int t = threadIdx.x, lane = t & 63, w = t >> 6;
  const int rowBase = blockIdx.x * 64;
  const int kBase = blockIdx.y * 2048;
  const int rr = lane & 15, gg8 = (lane >> 4) * 8;
  f32x4 acc0 = {}, acc1 = {};
  const unsigned short* b0P = wt_bf + (size_t)rr * LL;
  const unsigned short* b1P = wt_bf + (size_t)(16 + rr) * LL;
  for (int c = 0; c < 4; ++c) {
    const int k0 = kBase + c * 512;
    __syncthreads();
    #pragma unroll
    for (int u = 0; u < 32; ++u) {
      int unit = t + u * 256;
      int row = unit >> 7, col4 = unit & 127;
      size_t gi = (size_t)(rowBase + row) * LL + k0 + col4 * 4;
      f32x4 v = *(const f32x4*)&feat[gi];
      u16x4 o; o[0] = f2bf(v[0]); o[1] = f2bf(v[1]); o[2] = f2bf(v[2]); o[3] = f2bf(v[3]);
      *(u16x4*)&feat_bf[gi] = o;
      int byte = (row * 1024 + col4 * 8) ^ ((row & 7) << 4);
      *(u16x4*)((char*)alds + byte) = o;
    }
    __syncthreads();
    const int arow = w * 16 + rr;
    const char* aBase = (const char*)alds + arow * 1024;
    const int axor = (arow & 7) << 4;
    #pragma unroll 4
    for (int ks = 0; ks < 16; ++ks) {
      int abyte = ((ks * 32 + gg8) * 2) ^ axor;
      short8 av = *(const short8*)(aBase + abyte);
      short8 b0 = *(const short8*)(b0P + k0 + ks * 32 + gg8);
      short8 b1 = *(const short8*)(b1P + k0 + ks * 32 + gg8);
      acc0 = MFMA(av, b0, acc0);
      acc1 = MFMA(av, b1, acc1);
    }
  }
  const int orow = rowBase + w * 16 + (lane >> 4) * 4;
  float* P = attP + (size_t)blockIdx.y * (8192 * 32);
  #pragma unroll
  for (int j = 0; j < 4; ++j) {
    P[(size_t)(orow + j) * 32 + rr]      = acc0[j];
    P[(size_t)(orow + j) * 32 + 16 + rr] = acc1[j];
  }
}

// ---------------- K3: edge scores + BN + softmax (sums 2 attP partials) ----------------
__global__ __launch_bounds__(256) void k_edge(const float* __restrict__ attP,
    const float* __restrict__ bl, const float* __restrict__ br,
    const float* __restrict__ gamma, const float* __restrict__ beta,
    float* __restrict__ w_t) {
  __shared__ __align__(16) float attr[BB][20];
  __shared__ float el[NN][BB + 1];
  __shared__ float part[NN][4][2];
  __shared__ float sc[NN], sh[NN];
  int d = blockIdx.x, t = threadIdx.x;
  for (int i = t; i < 2048; i += 256) {
    int b = i >> 4, e = i & 15;
    float v2 = br[e];
    #pragma unroll
    for (int c = 0; c < 2; ++c)
      v2 += attP[(size_t)c * (8192 * 32) + ((size_t)d * 128 + b) * 32 + 16 + e];
    attr[b][e] = v2;
  }
  float blv[16];
  #pragma unroll
  for (int e = 0; e < 16; ++e) blv[e] = bl[e];
  __syncthreads();
  for (int v = t; v < NN * BB; v += 256) {
    int s = v >> 7, b = v & 127;
    float al[16];
    #pragma unroll
    for (int e = 0; e < 16; ++e) al[e] = blv[e];
    #pragma unroll
    for (int c = 0; c < 2; ++c) {
      const f32x4* p = (const f32x4*)&attP[(size_t)c * (8192 * 32) + ((size_t)s * 128 + b) * 32];
      #pragma unroll
      for (int q = 0; q < 4; ++q) {
        f32x4 x = p[q];
        al[q * 4 + 0] += x[0]; al[q * 4 + 1] += x[1];
        al[q * 4 + 2] += x[2]; al[q * 4 + 3] += x[3];
      }
    }
    float acc = 0.f;
    #pragma unroll
    for (int e = 0; e < 16; ++e) acc += al[e] * attr[b][e];
    el[s][b] = acc;
  }
  __syncthreads();
  {
    int s = t >> 2, q = t & 3;
    float sum = 0.f, ss = 0.f;
    for (int b = q * 32; b < q * 32 + 32; ++b) { float x = el[s][b]; sum += x; ss += x * x; }
    part[s][q][0] = sum; part[s][q][1] = ss;
  }
  __syncthreads();
  if (t < 64) {
    float sum = 0.f, ss = 0.f;
    #pragma unroll
    for (int q = 0; q < 4; ++q) { sum += part[t][q][0]; ss += part[t][q][1]; }
    float mu = sum * (1.f / 128.f);
    float var = ss * (1.f / 128.f) - mu * mu;
    int c = d * 64 + t;
    float a = gamma[c] * rsqrtf(fmaxf(var, 0.f) + 1e-5f);
    sc[t] = a; sh[t] = beta[c] - mu * a;
  }
  __syncthreads();
  if (t < 128) {
    int b = t;
    float y[64];
    float m = -1e30f;
    #pragma unroll
    for (int s = 0; s < 64; ++s) { y[s] = sc[s] * el[s][b] + sh[s]; m = fmaxf(m, y[s]); }
    float sum = 0.f;
    #pragma unroll
    for (int s = 0; s < 64; ++s) { y[s] = __expf(y[s] - m); sum += y[s]; }
    float inv = 1.f / sum;
    float* wp = &w_t[((size_t)b * 64 + d) * 64];
    #pragma unroll
    for (int s4 = 0; s4 < 16; ++s4) {
      f32x4 o;
      o[0] = y[s4 * 4 + 0] * inv; o[1] = y[s4 * 4 + 1] * inv;
      o[2] = y[s4 * 4 + 2] * inv; o[3] = y[s4 * 4 + 3] * inv;
      *(f32x4*)&wp[s4 * 4] = o;
    }
  }
}

// ---------------- K4: 256x256 GEMM, 4 waves of 128x128, mfma 32x32x16 ----------------
// R7->R8: attack the ADDITIVE LDS+MFMA budget (measured 295k+318k cyc/CU):
// (a) 128x128 per-wave tile cuts LDS read bytes 33% ((M+N)/(M*N) geometry);
// (b) 32x32x16 MFMA is ~17% less pipe time per FLOP (2382 vs 2075 TF ubench).
// acc = 4x4 x f32x16 = 256 VGPR, all static indexing. R7's proven 3-slot
// ring, 1 barrier/tile, counted VM8 (8 gloads/tile, stage t+2).
// Swizzle: rows 64B, 16B-slot ^= (row>>1)&3 -> 8 bank-phases x 4 lanes
// (b128 optimum); staging source uses inverse: s = (t&3) ^ ((t>>3)&3).
#define BAR   __builtin_amdgcn_s_barrier()
#define VM8   asm volatile("s_waitcnt vmcnt(8)" ::: "memory")
#define VM0   asm volatile("s_waitcnt vmcnt(0)" ::: "memory")
#define NOVM  do {} while (0)
#define PRIO1 __builtin_amdgcn_s_setprio(1)
#define PRIO0 __builtin_amdgcn_s_setprio(0)

#define STAGE8(STG, KK) do { \
    _Pragma("unroll") for (int i_ = 0; i_ < 4; ++i_) \
      gload16(aGs + (size_t)i_ * 64 * LL + (KK), ldsm + (STG) * 32768 + i_ * 4096 + tid16); \
    _Pragma("unroll") for (int i_ = 0; i_ < 4; ++i_) \
      gload16(bGs + (size_t)i_ * 64 * LL + (KK), ldsm + (STG) * 32768 + 16384 + i_ * 4096 + tid16); \
  } while (0)

#define GITER32(T, CUR, STG, DOSTAGE, VMW) do { \
    const char* pA = ldsm + (CUR) * 32768 + baseA; \
    const char* pB = ldsm + (CUR) * 32768 + baseB; \
    short8 af[4], bf[4]; \
    _Pragma("unroll") for (int mi = 0; mi < 4; ++mi) af[mi] = *(const short8*)(pA + mi * 2048 + offK0); \
    _Pragma("unroll") for (int nj = 0; nj < 4; ++nj) bf[nj] = *(const short8*)(pB + nj * 2048 + offK0); \
    if (DOSTAGE) { STAGE8(STG, (size_t)((T) + 2) * 32); } \
    PRIO1; \
    _Pragma("unroll") for (int mi = 0; mi < 4; ++mi) \
      _Pragma("unroll") for (int nj = 0; nj < 4; ++nj) \
        acc[mi][nj] = MFMA32(af[mi], bf[nj], acc[mi][nj]); \
    PRIO0; \
    _Pragma("unroll") for (int mi = 0; mi < 4; ++mi) af[mi] = *(const short8*)(pA + mi * 2048 + offK1); \
    _Pragma("unroll") for (int nj = 0; nj < 4; ++nj) bf[nj] = *(const short8*)(pB + nj * 2048 + offK1); \
    PRIO1; \
    _Pragma("unroll") for (int mi = 0; mi < 4; ++mi) \
      _Pragma("unroll") for (int nj = 0; nj < 4; ++nj) \
        acc[mi][nj] = MFMA32(af[mi], bf[nj], acc[mi][nj]); \
    PRIO0; VMW; BAR; \
  } while (0)

__global__ __launch_bounds__(256, 1) void k_gemm32(const unsigned short* __restrict__ A,
    const unsigned short* __restrict__ Bm, const float* __restrict__ bm,
    unsigned short* __restrict__ C) {
  __shared__ __align__(16) char ldsm[98304];
  const int tid = threadIdx.x;
  const int lane = tid & 63, wave = tid >> 6;
  const int wm = wave >> 1, wn = wave & 1;
  int bid = blockIdx.x;
  int swz = (bid & 7) * 64 + (bid >> 3);    // 512 % 8 == 0, bijective
  int tM = swz >> 4, tN = swz & 15;
  const size_t rowBase = (size_t)tM * 256, colBase = (size_t)tN * 256;
  // staging source (inverse swizzle; LDS dest linear)
  const int tid16 = tid * 16;
  const int srow = tid >> 2;                              // 0..63
  const int sslot = (tid & 3) ^ ((tid >> 3) & 3);         // k-group 0..3
  const unsigned short* aGs = A  + (rowBase + srow) * LL + sslot * 8;
  const unsigned short* bGs = Bm + (colBase + srow) * LL + sslot * 8;
  // ds_read lane constants
  const int lrow = lane & 31, lhw = lane >> 5, lw = (lane >> 1) & 3;
  const int baseA = (wm * 128 + lrow) * 64;
  const int baseB = 16384 + (wn * 128 + lrow) * 64;
  const int offK0 = ((lhw) ^ lw) * 16;
  const int offK1 = ((2 + lhw) ^ lw) * 16;
  f32x16 acc[4][4] = {};
  // ---- prologue: stage t0 -> slot0, t1 -> slot1 ----
  STAGE8(0, 0);
  STAGE8(1, 32);
  VM8;
  BAR;
  // ---- main loop: 128 K-tiles (BK=32), ring slot t%3, stage t+2 ----
  for (int tb = 0; tb < 126; tb += 3) {
    GITER32(tb,     0, 2, 1, VM8);
    GITER32(tb + 1, 1, 0, 1, VM8);
    GITER32(tb + 2, 2, 1, 1, VM8);
  }
  GITER32(126, 0, 0, 0, VM0);
  GITER32(127, 1, 0, 0, NOVM);
  // ---- epilogue: +bm, ReLU, bf16 store (32x32 C/D layout) ----
  const int cl = lane & 31, rh = (lane >> 5) * 4;
  float bcv[4];
  #pragma unroll
  for (int nj = 0; nj < 4; ++nj) bcv[nj] = bm[colBase + wn * 128 + nj * 32 + cl];
  #pragma unroll
  for (int mi = 0; mi < 4; ++mi) {
    #pragma unroll
    for (int nj = 0; nj < 4; ++nj) {
      size_t c = colBase + (size_t)wn * 128 + nj * 32 + cl;
      float bc = bcv[nj];
      #pragma unroll
      for (int r = 0; r < 16; ++r) {
        size_t row = rowBase + (size_t)wm * 128 + mi * 32 + (r & 3) + 8 * (r >> 2) + rh;
        float v = acc[mi][nj][r] + bc;
        v = fmaxf(v, 0.f);
        C[row * LL + c] = f2bf(v);
      }
    }
  }
}

// ---------------- K5: aggregation ----------------
__global__ __launch_bounds__(256) void k_agg2(const float* __restrict__ w_t,
    const unsigned short* __restrict__ outb, const float* __restrict__ bias,
    float* __restrict__ rst) {
  int b = blockIdx.y;
  int t = threadIdx.x;
  int l0 = blockIdx.x * 512 + t * 2;
  float oA[64], oB[64];
  #pragma unroll
  for (int s = 0; s < 64; ++s) {
    unsigned u = *(const unsigned*)&outb[((size_t)s * BB + b) * LL + l0];
    oA[s] = bf2f((unsigned short)(u & 0xFFFF));
    oB[s] = bf2f((unsigned short)(u >> 16));
  }
  const float* wb = w_t + (size_t)b * 4096;
  float bs0 = bias[l0], bs1 = bias[l0 + 1];
  #pragma unroll 2
  for (int d = 0; d < 64; ++d) {
    const float* wr = wb + d * 64;
    float a0 = 0.f, a1 = 0.f;
    #pragma unroll
    for (int q = 0; q < 16; ++q) {
      f32x4 wq = *(const f32x4*)&wr[q * 4];
      #pragma unroll
      for (int j = 0; j < 4; ++j) {
        float wv = wq[j];
        a0 += wv * oA[q * 4 + j];
        a1 += wv * oB[q * 4 + j];
      }
    }
    f32x2 o; o[0] = a0 + bs0; o[1] = a1 + bs1;
    *(f32x2*)&rst[((size_t)d * BB + b) * LL + l0] = o;
  }
}

extern "C" void kernel_launch(void* const* d_in, const int* in_sizes, int n_in,
                              void* d_out, int out_size, void* d_ws, size_t ws_size,
                              hipStream_t stream) {
  (void)in_sizes; (void)n_in; (void)out_size; (void)ws_size;
  const float* feat  = (const float*)d_in[0];
  const float* Wl    = (const float*)d_in[1];
  const float* bl    = (const float*)d_in[2];
  const float* Wr    = (const float*)d_in[3];
  const float* br    = (const float*)d_in[4];
  const float* Wm    = (const float*)d_in[5];
  const float* bm    = (const float*)d_in[6];
  const float* gamma = (const float*)d_in[7];
  const float* beta  = (const float*)d_in[8];
  const float* bias  = (const float*)d_in[9];
  char* ws = (char*)d_ws;
  unsigned short* feat_bf = (unsigned short*)(ws);                 // 67,108,864
  unsigned short* wm_bf   = (unsigned short*)(ws + 67108864ull);   // 33,554,432
  unsigned short* out_bf  = (unsigned short*)(ws + 100663296ull);  // 67,108,864
  float* attP  = (float*)(ws + 167772160ull);                      //  2,097,152
  float* w_t   = (float*)(ws + 169869312ull);                      //  2,097,152
  unsigned short* wt_bf = (unsigned short*)(ws + 171966464ull);    //    262,144
  float* rst = (float*)d_out;

  k_cvtw<<<dim3(2056), dim3(256), 0, stream>>>(Wm, Wl, Wr, wm_bf, wt_bf);
  k_attF<<<dim3(128, 2), dim3(256), 0, stream>>>(feat, wt_bf, feat_bf, attP);
  k_edge<<<dim3(64), dim3(256), 0, stream>>>(attP, bl, br, gamma, beta, w_t);
  k_gemm32<<<dim3(512), dim3(256), 0, stream>>>(feat_bf, wm_bf, bm, out_bf);
  k_agg2<<<dim3(8, 128), dim3(256), 0, stream>>>(w_t, out_bf, bias, rst);
}